// Round 1
// baseline (10231.521 us; speedup 1.0000x reference)
//
#include <hip/hip_runtime.h>
#include <cstdint>
#include <cstddef>

#define Bb 4
#define Nn 1024
#define Cc 1024
#define Hh 16
#define DHd 64
#define SCALE 0.125f   // DH^-0.5

// ===================== 128x128 fp32 GEMM core: out = A @ W^T =====================
// A: [M,1024] row-major, W: [1024,1024] row-major (nn.Linear weight), dot over rows of W.
__device__ __forceinline__ void gemm_tile(const float* __restrict__ A,
                                          const float* __restrict__ W,
                                          int m0, int n0,
                                          float (&acc)[8][8],
                                          float (*As)[132], float (*Bs)[132])
{
    const int tid  = threadIdx.x;
    const int row  = tid >> 1;   // 0..127
    const int half = tid & 1;    // 0..1
    const int tx   = tid & 15, ty = tid >> 4;
    for (int k0 = 0; k0 < Cc; k0 += 8) {
        float4 av = *(const float4*)(A + (size_t)(m0 + row) * Cc + k0 + half * 4);
        float4 bv = *(const float4*)(W + (size_t)(n0 + row) * Cc + k0 + half * 4);
        __syncthreads();
        As[half*4+0][row] = av.x; As[half*4+1][row] = av.y;
        As[half*4+2][row] = av.z; As[half*4+3][row] = av.w;
        Bs[half*4+0][row] = bv.x; Bs[half*4+1][row] = bv.y;
        Bs[half*4+2][row] = bv.z; Bs[half*4+3][row] = bv.w;
        __syncthreads();
        #pragma unroll
        for (int kk = 0; kk < 8; ++kk) {
            float4 a0 = *(const float4*)&As[kk][ty*8];
            float4 a1 = *(const float4*)&As[kk][ty*8+4];
            float4 b0 = *(const float4*)&Bs[kk][tx*8];
            float4 b1 = *(const float4*)&Bs[kk][tx*8+4];
            float ar[8] = {a0.x,a0.y,a0.z,a0.w,a1.x,a1.y,a1.z,a1.w};
            float br[8] = {b0.x,b0.y,b0.z,b0.w,b1.x,b1.y,b1.z,b1.w};
            #pragma unroll
            for (int i = 0; i < 8; ++i)
                #pragma unroll
                for (int j = 0; j < 8; ++j)
                    acc[i][j] += ar[i] * br[j];
        }
    }
}

// q/k/v projections with head split; z==2 adds Er_v (folds the VEr term into v).
__global__ __launch_bounds__(256, 2)
void gemm_qkv_kernel(const float* __restrict__ x,
                     const float* __restrict__ Wq, const float* __restrict__ Wk,
                     const float* __restrict__ Wv, const float* __restrict__ Ev,
                     float* __restrict__ q, float* __restrict__ k, float* __restrict__ vp)
{
    __shared__ float As[8][132];
    __shared__ float Bs[8][132];
    const int z = blockIdx.z;
    const float* W = (z == 0) ? Wq : (z == 1) ? Wk : Wv;
    float* outp    = (z == 0) ? q  : (z == 1) ? k  : vp;
    const int m0 = blockIdx.y * 128, n0 = blockIdx.x * 128;
    float acc[8][8] = {};
    gemm_tile(x, W, m0, n0, acc, As, Bs);
    const int tx = threadIdx.x & 15, ty = threadIdx.x >> 4;
    #pragma unroll
    for (int i = 0; i < 8; ++i) {
        const int t  = m0 + ty*8 + i;
        const int bb = t >> 10, ii = t & 1023;
        #pragma unroll
        for (int j4 = 0; j4 < 2; ++j4) {
            const int o  = n0 + tx*8 + j4*4;
            const int hh = o >> 6, dd = o & 63;
            float4 v = make_float4(acc[i][j4*4+0], acc[i][j4*4+1],
                                   acc[i][j4*4+2], acc[i][j4*4+3]);
            if (z == 2) {
                float4 e = *(const float4*)(Ev + (size_t)ii * DHd + dd);
                v.x += e.x; v.y += e.y; v.z += e.z; v.w += e.w;
            }
            *(float4*)(outp + (size_t)((bb*Hh + hh)*Nn + ii) * DHd + dd) = v;
        }
    }
}

// final projection: out = ctx @ Wp^T + bp
__global__ __launch_bounds__(256, 2)
void gemm_out_kernel(const float* __restrict__ ctx, const float* __restrict__ Wp,
                     const float* __restrict__ bp, float* __restrict__ out)
{
    __shared__ float As[8][132];
    __shared__ float Bs[8][132];
    const int m0 = blockIdx.y * 128, n0 = blockIdx.x * 128;
    float acc[8][8] = {};
    gemm_tile(ctx, Wp, m0, n0, acc, As, Bs);
    const int tx = threadIdx.x & 15, ty = threadIdx.x >> 4;
    #pragma unroll
    for (int i = 0; i < 8; ++i) {
        const int t = m0 + ty*8 + i;
        #pragma unroll
        for (int j4 = 0; j4 < 2; ++j4) {
            const int o = n0 + tx*8 + j4*4;
            float4 bb4 = *(const float4*)(bp + o);
            float4 v = make_float4(acc[i][j4*4+0]+bb4.x, acc[i][j4*4+1]+bb4.y,
                                   acc[i][j4*4+2]+bb4.z, acc[i][j4*4+3]+bb4.w);
            *(float4*)(out + (size_t)t * Cc + o) = v;
        }
    }
}

// ===================== fused relative attention =====================
// Per block: one (b,h) and 32 query rows. LDS: S[32][1024] (128KB) + 16KB swizzled stage.
// S[i][c] = q_i.k_c + skew(G)  with  G[i][j] = q_i.Eq[j] + k_i.Ek[j]
// skew(G)[i][c] : c<=i  -> G[i, N-1-i+c] ; c==i+1 -> 0 ; c>i+1 -> G[i+1, c-i-2]
// Equivalently scatter: G[li][j] -> S[li][j+i-(N-1)] (if >=0)  and  S[li-1][j+i+1] (if <N)
__global__ __launch_bounds__(512, 1)
void attn_kernel(const float* __restrict__ q, const float* __restrict__ k,
                 const float* __restrict__ vp, const float* __restrict__ Eq,
                 const float* __restrict__ Ek, float* __restrict__ ctx)
{
    extern __shared__ float lds[];
    float* S   = lds;               // [32][1024]
    float* stg = lds + 32 * 1024;   // [64][64], xor-swizzled: elem (r,d) at r*64 + (d ^ (r&31))
    const int tid  = threadIdx.x;
    const int lane = tid & 63;
    const int wv   = tid >> 6;      // 0..7
    const int sw   = lane & 31;
    const int i0   = blockIdx.x * 32;
    const int bh   = blockIdx.y;
    const int b    = bh >> 4, h = bh & 15;
    const float* qb = q  + (size_t)bh * Nn * DHd;
    const float* kb = k  + (size_t)bh * Nn * DHd;
    const float* vb = vp + (size_t)bh * Nn * DHd;
    const int r0 = wv * 4;          // this wave's 4 S-rows

    const float* q0 = qb + (size_t)(i0 + r0 + 0) * DHd;
    const float* q1 = qb + (size_t)(i0 + r0 + 1) * DHd;
    const float* q2 = qb + (size_t)(i0 + r0 + 2) * DHd;
    const float* q3 = qb + (size_t)(i0 + r0 + 3) * DHd;
    const float* k0r = kb + (size_t)(i0 + r0 + 0) * DHd;
    const float* k1r = kb + (size_t)(i0 + r0 + 1) * DHd;
    const float* k2r = kb + (size_t)(i0 + r0 + 2) * DHd;
    const float* k3r = kb + (size_t)(i0 + r0 + 3) * DHd;

    // ---------- Phase 1: S = q @ k^T ----------
    for (int c0 = 0; c0 < Nn; c0 += 64) {
        __syncthreads();
        #pragma unroll
        for (int p = 0; p < 8; ++p) {
            const int cc = wv + p * 8;
            stg[cc * 64 + (lane ^ (cc & 31))] = kb[(size_t)(c0 + cc) * DHd + lane];
        }
        __syncthreads();
        float a0 = 0.f, a1 = 0.f, a2 = 0.f, a3 = 0.f;
        const float* krow = stg + lane * 64;       // this lane's key row (c = c0+lane)
        #pragma unroll
        for (int d4 = 0; d4 < 16; ++d4) {
            const float k0v = krow[(d4*4+0) ^ sw];
            const float k1v = krow[(d4*4+1) ^ sw];
            const float k2v = krow[(d4*4+2) ^ sw];
            const float k3v = krow[(d4*4+3) ^ sw];
            float4 v0 = *(const float4*)(q0 + d4*4);
            float4 v1 = *(const float4*)(q1 + d4*4);
            float4 v2 = *(const float4*)(q2 + d4*4);
            float4 v3 = *(const float4*)(q3 + d4*4);
            a0 += v0.x*k0v + v0.y*k1v + v0.z*k2v + v0.w*k3v;
            a1 += v1.x*k0v + v1.y*k1v + v1.z*k2v + v1.w*k3v;
            a2 += v2.x*k0v + v2.y*k1v + v2.z*k2v + v2.w*k3v;
            a3 += v3.x*k0v + v3.y*k1v + v3.z*k2v + v3.w*k3v;
        }
        S[(r0+0)*1024 + c0 + lane] = a0;
        S[(r0+1)*1024 + c0 + lane] = a1;
        S[(r0+2)*1024 + c0 + lane] = a2;
        S[(r0+3)*1024 + c0 + lane] = a3;
    }

    // ---------- Phase 2: G = q.Eq^T + k.Ek^T, scattered (skew) into S ----------
    const bool has5 = (wv == 7) && (i0 + 32 < Nn);   // extra G row i0+32
    for (int j0 = 0; j0 < Nn; j0 += 64) {
        float g0=0.f, g1=0.f, g2=0.f, g3=0.f, g4=0.f;
        // pass A: Eq with q rows
        __syncthreads();
        #pragma unroll
        for (int p = 0; p < 8; ++p) {
            const int jj = wv + p * 8;
            stg[jj * 64 + (lane ^ (jj & 31))] = Eq[(size_t)(j0 + jj) * DHd + lane];
        }
        __syncthreads();
        {
            const float* er = stg + lane * 64;     // Er row j = j0+lane
            #pragma unroll
            for (int d4 = 0; d4 < 16; ++d4) {
                const float e0 = er[(d4*4+0) ^ sw];
                const float e1 = er[(d4*4+1) ^ sw];
                const float e2 = er[(d4*4+2) ^ sw];
                const float e3 = er[(d4*4+3) ^ sw];
                float4 v0 = *(const float4*)(q0 + d4*4);
                float4 v1 = *(const float4*)(q1 + d4*4);
                float4 v2 = *(const float4*)(q2 + d4*4);
                float4 v3 = *(const float4*)(q3 + d4*4);
                g0 += v0.x*e0 + v0.y*e1 + v0.z*e2 + v0.w*e3;
                g1 += v1.x*e0 + v1.y*e1 + v1.z*e2 + v1.w*e3;
                g2 += v2.x*e0 + v2.y*e1 + v2.z*e2 + v2.w*e3;
                g3 += v3.x*e0 + v3.y*e1 + v3.z*e2 + v3.w*e3;
            }
            if (has5) {
                const float* q4p = qb + (size_t)(i0 + 32) * DHd;
                #pragma unroll
                for (int d4 = 0; d4 < 16; ++d4) {
                    const float e0 = er[(d4*4+0) ^ sw];
                    const float e1 = er[(d4*4+1) ^ sw];
                    const float e2 = er[(d4*4+2) ^ sw];
                    const float e3 = er[(d4*4+3) ^ sw];
                    float4 v4 = *(const float4*)(q4p + d4*4);
                    g4 += v4.x*e0 + v4.y*e1 + v4.z*e2 + v4.w*e3;
                }
            }
        }
        // pass B: Ek with k rows
        __syncthreads();
        #pragma unroll
        for (int p = 0; p < 8; ++p) {
            const int jj = wv + p * 8;
            stg[jj * 64 + (lane ^ (jj & 31))] = Ek[(size_t)(j0 + jj) * DHd + lane];
        }
        __syncthreads();
        {
            const float* er = stg + lane * 64;
            #pragma unroll
            for (int d4 = 0; d4 < 16; ++d4) {
                const float e0 = er[(d4*4+0) ^ sw];
                const float e1 = er[(d4*4+1) ^ sw];
                const float e2 = er[(d4*4+2) ^ sw];
                const float e3 = er[(d4*4+3) ^ sw];
                float4 v0 = *(const float4*)(k0r + d4*4);
                float4 v1 = *(const float4*)(k1r + d4*4);
                float4 v2 = *(const float4*)(k2r + d4*4);
                float4 v3 = *(const float4*)(k3r + d4*4);
                g0 += v0.x*e0 + v0.y*e1 + v0.z*e2 + v0.w*e3;
                g1 += v1.x*e0 + v1.y*e1 + v1.z*e2 + v1.w*e3;
                g2 += v2.x*e0 + v2.y*e1 + v2.z*e2 + v2.w*e3;
                g3 += v3.x*e0 + v3.y*e1 + v3.z*e2 + v3.w*e3;
            }
            if (has5) {
                const float* k4p = kb + (size_t)(i0 + 32) * DHd;
                #pragma unroll
                for (int d4 = 0; d4 < 16; ++d4) {
                    const float e0 = er[(d4*4+0) ^ sw];
                    const float e1 = er[(d4*4+1) ^ sw];
                    const float e2 = er[(d4*4+2) ^ sw];
                    const float e3 = er[(d4*4+3) ^ sw];
                    float4 v4 = *(const float4*)(k4p + d4*4);
                    g4 += v4.x*e0 + v4.y*e1 + v4.z*e2 + v4.w*e3;
                }
            }
        }
        // scatter (all target addresses provably disjoint across lanes & waves)
        const int j = j0 + lane;
        #pragma unroll
        for (int r = 0; r < 4; ++r) {
            const float gv = (r==0) ? g0 : (r==1) ? g1 : (r==2) ? g2 : g3;
            const int li = r0 + r;
            const int i  = i0 + li;
            const int c1 = j + i - (Nn - 1);
            if (c1 >= 0) S[li*1024 + c1] += gv;                 // c<=i branch
            const int c2 = j + i + 1;
            if (li >= 1 && c2 < Nn) S[(li-1)*1024 + c2] += gv;  // c>i+1 branch (row above)
        }
        if (has5) {
            const int i  = i0 + 32;
            const int c2 = j + i + 1;
            if (c2 < Nn) S[31*1024 + c2] += g4;
        }
    }

    // ---------- Phase 3: row softmax (scale applied inside exp) ----------
    __syncthreads();
    #pragma unroll
    for (int rr = 0; rr < 4; ++rr) {
        float* Srow = S + (size_t)(r0 + rr) * 1024;
        float vals[16];
        float m = -3.0e38f;
        #pragma unroll
        for (int kx = 0; kx < 16; ++kx) { vals[kx] = Srow[lane + kx*64]; m = fmaxf(m, vals[kx]); }
        #pragma unroll
        for (int off = 32; off >= 1; off >>= 1) m = fmaxf(m, __shfl_xor(m, off));
        float sum = 0.f;
        #pragma unroll
        for (int kx = 0; kx < 16; ++kx) { vals[kx] = __expf((vals[kx] - m) * SCALE); sum += vals[kx]; }
        #pragma unroll
        for (int off = 32; off >= 1; off >>= 1) sum += __shfl_xor(sum, off);
        const float inv = 1.0f / sum;
        #pragma unroll
        for (int kx = 0; kx < 16; ++kx) Srow[lane + kx*64] = vals[kx] * inv;
    }

    // ---------- Phase 4: ctx = P @ (v + Er_v) ----------
    float o0=0.f, o1=0.f, o2=0.f, o3=0.f;
    for (int c0 = 0; c0 < Nn; c0 += 64) {
        __syncthreads();
        #pragma unroll
        for (int p = 0; p < 8; ++p) {
            const int cc = wv + p * 8;
            stg[cc * 64 + (lane ^ (cc & 31))] = vb[(size_t)(c0 + cc) * DHd + lane];
        }
        __syncthreads();
        #pragma unroll
        for (int c4 = 0; c4 < 16; ++c4) {
            float4 p0 = *(const float4*)(S + (r0+0)*1024 + c0 + c4*4);
            float4 p1 = *(const float4*)(S + (r0+1)*1024 + c0 + c4*4);
            float4 p2 = *(const float4*)(S + (r0+2)*1024 + c0 + c4*4);
            float4 p3 = *(const float4*)(S + (r0+3)*1024 + c0 + c4*4);
            const int cA = c4*4+0, cB = c4*4+1, cC = c4*4+2, cD = c4*4+3;
            const float vA = stg[cA*64 + (lane ^ (cA & 31))];
            const float vB = stg[cB*64 + (lane ^ (cB & 31))];
            const float vC = stg[cC*64 + (lane ^ (cC & 31))];
            const float vD = stg[cD*64 + (lane ^ (cD & 31))];
            o0 += p0.x*vA + p0.y*vB + p0.z*vC + p0.w*vD;
            o1 += p1.x*vA + p1.y*vB + p1.z*vC + p1.w*vD;
            o2 += p2.x*vA + p2.y*vB + p2.z*vC + p2.w*vD;
            o3 += p3.x*vA + p3.y*vB + p3.z*vC + p3.w*vD;
        }
    }
    const size_t tb = (size_t)b * Nn + i0 + r0;
    ctx[(tb+0)*Cc + h*64 + lane] = o0;
    ctx[(tb+1)*Cc + h*64 + lane] = o1;
    ctx[(tb+2)*Cc + h*64 + lane] = o2;
    ctx[(tb+3)*Cc + h*64 + lane] = o3;
}

// ===================== host =====================
extern "C" void kernel_launch(void* const* d_in, const int* in_sizes, int n_in,
                              void* d_out, int out_size, void* d_ws, size_t ws_size,
                              hipStream_t stream)
{
    const float* x  = (const float*)d_in[0];
    const float* Wq = (const float*)d_in[1];
    const float* Wk = (const float*)d_in[2];
    const float* Wv = (const float*)d_in[3];
    const float* Eq = (const float*)d_in[4];
    const float* Ek = (const float*)d_in[5];
    const float* Ev = (const float*)d_in[6];
    const float* Wp = (const float*)d_in[7];
    const float* bp = (const float*)d_in[8];
    float* out = (float*)d_out;
    float* ws  = (float*)d_ws;

    // workspace layout (floats): q, k, v+Ev, ctx — 4 x 4,194,304 = 64 MiB
    float* q   = ws;
    float* k   = ws + (size_t)4194304;
    float* vp  = ws + (size_t)2 * 4194304;
    float* ctx = ws + (size_t)3 * 4194304;

    (void)hipFuncSetAttribute((const void*)attn_kernel,
                              hipFuncAttributeMaxDynamicSharedMemorySize, 147456);

    gemm_qkv_kernel<<<dim3(8, 32, 3), 256, 0, stream>>>(x, Wq, Wk, Wv, Ev, q, k, vp);
    attn_kernel<<<dim3(32, 64), 512, 147456, stream>>>(q, k, vp, Eq, Ek, ctx);
    gemm_out_kernel<<<dim3(8, 32, 1), 256, 0, stream>>>(ctx, Wp, bp, out);
}

// Round 3
// 2019.464 us; speedup vs baseline: 5.0665x; 5.0665x over previous
//
#include <hip/hip_runtime.h>
#include <cstdint>
#include <cstddef>

#define Bb 4
#define Nn 1024
#define Cc 1024
#define Hh 16
#define DHd 64
#define SCALE 0.125f   // DH^-0.5

// ===================== 128x128 fp32 GEMM core: out = A @ W^T =====================
__device__ __forceinline__ void gemm_tile(const float* __restrict__ A,
                                          const float* __restrict__ W,
                                          int m0, int n0,
                                          float (&acc)[8][8],
                                          float (*As)[132], float (*Bs)[132])
{
    const int tid  = threadIdx.x;
    const int row  = tid >> 1;
    const int half = tid & 1;
    const int tx   = tid & 15, ty = tid >> 4;
    for (int k0 = 0; k0 < Cc; k0 += 8) {
        float4 av = *(const float4*)(A + (size_t)(m0 + row) * Cc + k0 + half * 4);
        float4 bv = *(const float4*)(W + (size_t)(n0 + row) * Cc + k0 + half * 4);
        __syncthreads();
        As[half*4+0][row] = av.x; As[half*4+1][row] = av.y;
        As[half*4+2][row] = av.z; As[half*4+3][row] = av.w;
        Bs[half*4+0][row] = bv.x; Bs[half*4+1][row] = bv.y;
        Bs[half*4+2][row] = bv.z; Bs[half*4+3][row] = bv.w;
        __syncthreads();
        #pragma unroll
        for (int kk = 0; kk < 8; ++kk) {
            float4 a0 = *(const float4*)&As[kk][ty*8];
            float4 a1 = *(const float4*)&As[kk][ty*8+4];
            float4 b0 = *(const float4*)&Bs[kk][tx*8];
            float4 b1 = *(const float4*)&Bs[kk][tx*8+4];
            float ar[8] = {a0.x,a0.y,a0.z,a0.w,a1.x,a1.y,a1.z,a1.w};
            float br[8] = {b0.x,b0.y,b0.z,b0.w,b1.x,b1.y,b1.z,b1.w};
            #pragma unroll
            for (int i = 0; i < 8; ++i)
                #pragma unroll
                for (int j = 0; j < 8; ++j)
                    acc[i][j] += ar[i] * br[j];
        }
    }
}

__global__ __launch_bounds__(256, 2)
void gemm_qkv_kernel(const float* __restrict__ x,
                     const float* __restrict__ Wq, const float* __restrict__ Wk,
                     const float* __restrict__ Wv, const float* __restrict__ Ev,
                     float* __restrict__ q, float* __restrict__ k, float* __restrict__ vp)
{
    __shared__ float As[8][132];
    __shared__ float Bs[8][132];
    const int z = blockIdx.z;
    const float* W = (z == 0) ? Wq : (z == 1) ? Wk : Wv;
    float* outp    = (z == 0) ? q  : (z == 1) ? k  : vp;
    const int m0 = blockIdx.y * 128, n0 = blockIdx.x * 128;
    float acc[8][8] = {};
    gemm_tile(x, W, m0, n0, acc, As, Bs);
    const int tx = threadIdx.x & 15, ty = threadIdx.x >> 4;
    #pragma unroll
    for (int i = 0; i < 8; ++i) {
        const int t  = m0 + ty*8 + i;
        const int bb = t >> 10, ii = t & 1023;
        #pragma unroll
        for (int j4 = 0; j4 < 2; ++j4) {
            const int o  = n0 + tx*8 + j4*4;
            const int hh = o >> 6, dd = o & 63;
            float4 v = make_float4(acc[i][j4*4+0], acc[i][j4*4+1],
                                   acc[i][j4*4+2], acc[i][j4*4+3]);
            if (z == 2) {
                float4 e = *(const float4*)(Ev + (size_t)ii * DHd + dd);
                v.x += e.x; v.y += e.y; v.z += e.z; v.w += e.w;
            }
            *(float4*)(outp + (size_t)((bb*Hh + hh)*Nn + ii) * DHd + dd) = v;
        }
    }
}

__global__ __launch_bounds__(256, 2)
void gemm_out_kernel(const float* __restrict__ ctx, const float* __restrict__ Wp,
                     const float* __restrict__ bp, float* __restrict__ out)
{
    __shared__ float As[8][132];
    __shared__ float Bs[8][132];
    const int m0 = blockIdx.y * 128, n0 = blockIdx.x * 128;
    float acc[8][8] = {};
    gemm_tile(ctx, Wp, m0, n0, acc, As, Bs);
    const int tx = threadIdx.x & 15, ty = threadIdx.x >> 4;
    #pragma unroll
    for (int i = 0; i < 8; ++i) {
        const int t = m0 + ty*8 + i;
        #pragma unroll
        for (int j4 = 0; j4 < 2; ++j4) {
            const int o = n0 + tx*8 + j4*4;
            float4 bb4 = *(const float4*)(bp + o);
            float4 v = make_float4(acc[i][j4*4+0]+bb4.x, acc[i][j4*4+1]+bb4.y,
                                   acc[i][j4*4+2]+bb4.z, acc[i][j4*4+3]+bb4.w);
            *(float4*)(out + (size_t)t * Cc + o) = v;
        }
    }
}

// ===================== fused relative attention (v2) =====================
// Per block: (b,h), 32 query rows. 512 thr / 8 waves.
// LDS: S[32][1024] (128K) + bufA[64][64] + bufB[64][64] (16K each, XOR-swizzled) = 160 KiB.
// Broadcast operands (q/k rows) read wave-uniformly from global (scalarizable).
// Streamed operands (k/Eq/Ek/v tiles) double-buffered in swizzled LDS, reg-staged.
__global__ __launch_bounds__(512, 2)
void attn_kernel(const float* __restrict__ q, const float* __restrict__ k,
                 const float* __restrict__ vp, const float* __restrict__ Eq,
                 const float* __restrict__ Ek, float* __restrict__ ctx)
{
    extern __shared__ float lds[];
    float* S    = lds;               // [32][1024]
    float* bufA = lds + 32 * 1024;   // [64][64] swizzled: elem (r,d) at r*64 + (d ^ ((r&7)<<2))
    float* bufB = bufA + 64 * 64;

    const int tid  = threadIdx.x;
    const int lane = tid & 63;
    const int wv   = __builtin_amdgcn_readfirstlane(tid >> 6);   // wave-uniform
    const int i0   = blockIdx.x * 32;
    const int bh   = blockIdx.y;
    const int b    = bh >> 4, h = bh & 15;
    const float* __restrict__ qb = q  + (size_t)bh * Nn * DHd;
    const float* __restrict__ kb = k  + (size_t)bh * Nn * DHd;
    const float* __restrict__ vb = vp + (size_t)bh * Nn * DHd;
    const int r0 = wv * 4;                 // this wave's 4 S-rows
    const int kx = (lane & 7) << 2;        // swizzle for this lane's own row (row==lane)

    // staging coords: thread covers rows (tid>>4) and (tid>>4)+32, float-group (tid&15)*4
    const int srow  = tid >> 4;
    const int scol4 = (tid & 15) * 4;
    const int sdst0 = srow * 64 + (scol4 ^ ((srow & 7) << 2));
    const int sdst1 = sdst0 + 32 * 64;     // ((srow+32)&7)==(srow&7)

    // wave-uniform q/k row pointers (scalarizable loads)
    const float* __restrict__ qr0 = qb + (size_t)(i0 + r0 + 0) * DHd;
    const float* __restrict__ qr1 = qb + (size_t)(i0 + r0 + 1) * DHd;
    const float* __restrict__ qr2 = qb + (size_t)(i0 + r0 + 2) * DHd;
    const float* __restrict__ qr3 = qb + (size_t)(i0 + r0 + 3) * DHd;
    const float* __restrict__ kr0 = kb + (size_t)(i0 + r0 + 0) * DHd;
    const float* __restrict__ kr1 = kb + (size_t)(i0 + r0 + 1) * DHd;
    const float* __restrict__ kr2 = kb + (size_t)(i0 + r0 + 2) * DHd;
    const float* __restrict__ kr3 = kb + (size_t)(i0 + r0 + 3) * DHd;

    float4 ra, rb;

    // ---------------- Phase 1: S = q @ k^T (double-buffered k tiles) ----------------
    ra = *(const float4*)(kb + (size_t)srow * 64 + scol4);
    rb = *(const float4*)(kb + (size_t)(srow + 32) * 64 + scol4);
    *(float4*)(bufA + sdst0) = ra;
    *(float4*)(bufA + sdst1) = rb;

    #pragma unroll 2
    for (int t = 0; t < 16; ++t) {
        float* cur = (t & 1) ? bufB : bufA;
        float* nxt = (t & 1) ? bufA : bufB;
        if (t < 15) {
            const float* src = kb + (size_t)(t + 1) * 64 * 64;
            ra = *(const float4*)(src + (size_t)srow * 64 + scol4);
            rb = *(const float4*)(src + (size_t)(srow + 32) * 64 + scol4);
        }
        __syncthreads();
        float a0 = 0.f, a1 = 0.f, a2 = 0.f, a3 = 0.f;
        const float* krow = cur + lane * 64;
        #pragma unroll
        for (int g = 0; g < 16; ++g) {
            float4 kv = *(const float4*)(krow + ((g * 4) ^ kx));
            float4 q0 = *(const float4*)(qr0 + g * 4);
            float4 q1 = *(const float4*)(qr1 + g * 4);
            float4 q2 = *(const float4*)(qr2 + g * 4);
            float4 q3 = *(const float4*)(qr3 + g * 4);
            a0 += q0.x*kv.x + q0.y*kv.y + q0.z*kv.z + q0.w*kv.w;
            a1 += q1.x*kv.x + q1.y*kv.y + q1.z*kv.z + q1.w*kv.w;
            a2 += q2.x*kv.x + q2.y*kv.y + q2.z*kv.z + q2.w*kv.w;
            a3 += q3.x*kv.x + q3.y*kv.y + q3.z*kv.z + q3.w*kv.w;
        }
        S[(r0+0)*1024 + t*64 + lane] = a0;
        S[(r0+1)*1024 + t*64 + lane] = a1;
        S[(r0+2)*1024 + t*64 + lane] = a2;
        S[(r0+3)*1024 + t*64 + lane] = a3;
        __syncthreads();
        if (t < 15) {
            *(float4*)(nxt + sdst0) = ra;
            *(float4*)(nxt + sdst1) = rb;
        }
    }

    // ---------------- Phase 2: G = q.Eq^T + k.Ek^T, skew-scattered into S ----------------
    // G rows gr = wv*4+rr (0..31); extra row gr=32 on wave 7 when i0+32 < N.
    // scatter: G[gr][j] -> S[gr][j+i-1023] (if >=0) and S[gr-1][j+i+1] (if <N), i=i0+gr.
    const bool hasx = (i0 + 32) < Nn;
    for (int t = 0; t < 16; ++t) {
        const float* eqs = Eq + (size_t)t * 64 * 64;
        const float* eks = Ek + (size_t)t * 64 * 64;
        float4 ea0 = *(const float4*)(eqs + (size_t)srow * 64 + scol4);
        float4 ea1 = *(const float4*)(eqs + (size_t)(srow + 32) * 64 + scol4);
        float4 eb0 = *(const float4*)(eks + (size_t)srow * 64 + scol4);
        float4 eb1 = *(const float4*)(eks + (size_t)(srow + 32) * 64 + scol4);
        __syncthreads();   // previous tile's compute+scatter done
        *(float4*)(bufA + sdst0) = ea0;
        *(float4*)(bufA + sdst1) = ea1;
        *(float4*)(bufB + sdst0) = eb0;
        *(float4*)(bufB + sdst1) = eb1;
        __syncthreads();

        float g0 = 0.f, g1 = 0.f, g2 = 0.f, g3 = 0.f;
        const float* ea = bufA + lane * 64;   // Eq row j = t*64+lane
        const float* eb = bufB + lane * 64;   // Ek row j
        #pragma unroll
        for (int g = 0; g < 16; ++g) {
            float4 eqv = *(const float4*)(ea + ((g * 4) ^ kx));
            float4 ekv = *(const float4*)(eb + ((g * 4) ^ kx));
            float4 q0 = *(const float4*)(qr0 + g * 4);
            float4 q1 = *(const float4*)(qr1 + g * 4);
            float4 q2 = *(const float4*)(qr2 + g * 4);
            float4 q3 = *(const float4*)(qr3 + g * 4);
            float4 k0 = *(const float4*)(kr0 + g * 4);
            float4 k1 = *(const float4*)(kr1 + g * 4);
            float4 k2 = *(const float4*)(kr2 + g * 4);
            float4 k3 = *(const float4*)(kr3 + g * 4);
            g0 += q0.x*eqv.x + q0.y*eqv.y + q0.z*eqv.z + q0.w*eqv.w
                + k0.x*ekv.x + k0.y*ekv.y + k0.z*ekv.z + k0.w*ekv.w;
            g1 += q1.x*eqv.x + q1.y*eqv.y + q1.z*eqv.z + q1.w*eqv.w
                + k1.x*ekv.x + k1.y*ekv.y + k1.z*ekv.z + k1.w*ekv.w;
            g2 += q2.x*eqv.x + q2.y*eqv.y + q2.z*eqv.z + q2.w*eqv.w
                + k2.x*ekv.x + k2.y*ekv.y + k2.z*ekv.z + k2.w*ekv.w;
            g3 += q3.x*eqv.x + q3.y*eqv.y + q3.z*eqv.z + q3.w*eqv.w
                + k3.x*ekv.x + k3.y*ekv.y + k3.z*ekv.z + k3.w*ekv.w;
        }
        const int j = t * 64 + lane;
        {
            const int gr = r0 + 0, i = i0 + gr;
            const int c1 = j + i - (Nn - 1);
            if (c1 >= 0) S[gr*1024 + c1] += g0;
            const int c2 = j + i + 1;
            if (gr >= 1 && c2 < Nn) S[(gr-1)*1024 + c2] += g0;
        }
        {
            const int gr = r0 + 1, i = i0 + gr;
            const int c1 = j + i - (Nn - 1);
            if (c1 >= 0) S[gr*1024 + c1] += g1;
            const int c2 = j + i + 1;
            if (c2 < Nn) S[(gr-1)*1024 + c2] += g1;
        }
        {
            const int gr = r0 + 2, i = i0 + gr;
            const int c1 = j + i - (Nn - 1);
            if (c1 >= 0) S[gr*1024 + c1] += g2;
            const int c2 = j + i + 1;
            if (c2 < Nn) S[(gr-1)*1024 + c2] += g2;
        }
        {
            const int gr = r0 + 3, i = i0 + gr;
            const int c1 = j + i - (Nn - 1);
            if (c1 >= 0) S[gr*1024 + c1] += g3;
            const int c2 = j + i + 1;
            if (c2 < Nn) S[(gr-1)*1024 + c2] += g3;
        }
        if (wv == 7 && hasx) {   // extra G row gr=32 -> only the "row above" target (row 31)
            const float* q4 = qb + (size_t)(i0 + 32) * DHd;
            const float* k4 = kb + (size_t)(i0 + 32) * DHd;
            float g4 = 0.f;
            #pragma unroll
            for (int g = 0; g < 16; ++g) {
                float4 eqv = *(const float4*)(ea + ((g * 4) ^ kx));
                float4 ekv = *(const float4*)(eb + ((g * 4) ^ kx));
                float4 qv = *(const float4*)(q4 + g * 4);
                float4 kv = *(const float4*)(k4 + g * 4);
                g4 += qv.x*eqv.x + qv.y*eqv.y + qv.z*eqv.z + qv.w*eqv.w
                    + kv.x*ekv.x + kv.y*ekv.y + kv.z*ekv.z + kv.w*ekv.w;
            }
            const int c2 = j + (i0 + 32) + 1;
            if (c2 < Nn) S[31*1024 + c2] += g4;
        }
    }
    __syncthreads();

    // ---------------- Phase 3: row softmax ----------------
    #pragma unroll
    for (int rr = 0; rr < 4; ++rr) {
        float* Srow = S + (size_t)(r0 + rr) * 1024;
        float vals[16];
        float m = -3.0e38f;
        #pragma unroll
        for (int x = 0; x < 16; ++x) { vals[x] = Srow[lane + x*64]; m = fmaxf(m, vals[x]); }
        #pragma unroll
        for (int off = 32; off >= 1; off >>= 1) m = fmaxf(m, __shfl_xor(m, off));
        float sum = 0.f;
        #pragma unroll
        for (int x = 0; x < 16; ++x) { vals[x] = __expf((vals[x] - m) * SCALE); sum += vals[x]; }
        #pragma unroll
        for (int off = 32; off >= 1; off >>= 1) sum += __shfl_xor(sum, off);
        const float inv = 1.0f / sum;
        #pragma unroll
        for (int x = 0; x < 16; ++x) Srow[lane + x*64] = vals[x] * inv;
    }
    // no barrier needed: P4 reads only this wave's own S rows; bufA overwrite is
    // covered by the in-loop barrier below.

    // ---------------- Phase 4: ctx = P @ (v+Ev), c-sub x d-sub decomposition ----------------
    // lane: csub = lane&15 (cols csub+16k), dg = lane>>4 (d-range dg*16..+15)
    const int csub = lane & 15;
    const int dg   = (lane >> 4) * 16;
    float op[4][16];
    #pragma unroll
    for (int r = 0; r < 4; ++r)
        #pragma unroll
        for (int d = 0; d < 16; ++d) op[r][d] = 0.f;

    ra = *(const float4*)(vb + (size_t)srow * 64 + scol4);
    rb = *(const float4*)(vb + (size_t)(srow + 32) * 64 + scol4);
    *(float4*)(bufA + sdst0) = ra;
    *(float4*)(bufA + sdst1) = rb;

    #pragma unroll 2
    for (int t = 0; t < 16; ++t) {
        float* cur = (t & 1) ? bufB : bufA;
        float* nxt = (t & 1) ? bufA : bufB;
        if (t < 15) {
            const float* src = vb + (size_t)(t + 1) * 64 * 64;
            ra = *(const float4*)(src + (size_t)srow * 64 + scol4);
            rb = *(const float4*)(src + (size_t)(srow + 32) * 64 + scol4);
        }
        __syncthreads();
        #pragma unroll
        for (int cq = 0; cq < 4; ++cq) {
            const int cl = csub + 16 * cq;            // local col in tile
            const float* vrow = cur + cl * 64;
            const int vx = (cl & 7) << 2;
            const float p0 = S[(r0+0)*1024 + t*64 + cl];
            const float p1 = S[(r0+1)*1024 + t*64 + cl];
            const float p2 = S[(r0+2)*1024 + t*64 + cl];
            const float p3 = S[(r0+3)*1024 + t*64 + cl];
            #pragma unroll
            for (int jj = 0; jj < 4; ++jj) {
                float4 vv = *(const float4*)(vrow + ((dg + 4*jj) ^ vx));
                op[0][4*jj+0] += p0 * vv.x; op[0][4*jj+1] += p0 * vv.y;
                op[0][4*jj+2] += p0 * vv.z; op[0][4*jj+3] += p0 * vv.w;
                op[1][4*jj+0] += p1 * vv.x; op[1][4*jj+1] += p1 * vv.y;
                op[1][4*jj+2] += p1 * vv.z; op[1][4*jj+3] += p1 * vv.w;
                op[2][4*jj+0] += p2 * vv.x; op[2][4*jj+1] += p2 * vv.y;
                op[2][4*jj+2] += p2 * vv.z; op[2][4*jj+3] += p2 * vv.w;
                op[3][4*jj+0] += p3 * vv.x; op[3][4*jj+1] += p3 * vv.y;
                op[3][4*jj+2] += p3 * vv.z; op[3][4*jj+3] += p3 * vv.w;
            }
        }
        __syncthreads();
        if (t < 15) {
            *(float4*)(nxt + sdst0) = ra;
            *(float4*)(nxt + sdst1) = rb;
        }
    }

    // reduce across the 16-lane group (lanes sharing dg, covering csub 0..15)
    #pragma unroll
    for (int off = 1; off <= 8; off <<= 1)
        #pragma unroll
        for (int r = 0; r < 4; ++r)
            #pragma unroll
            for (int d = 0; d < 16; ++d)
                op[r][d] += __shfl_xor(op[r][d], off);

    // writers: lane = g*16 + r (r<4) writes row r0+r, d-range g*16..+15
    #pragma unroll
    for (int r = 0; r < 4; ++r) {
        if ((lane & 15) == r) {
            float* dst = ctx + ((size_t)b * Nn + i0 + r0 + r) * Cc + h * 64 + dg;
            *(float4*)(dst + 0)  = make_float4(op[r][0],  op[r][1],  op[r][2],  op[r][3]);
            *(float4*)(dst + 4)  = make_float4(op[r][4],  op[r][5],  op[r][6],  op[r][7]);
            *(float4*)(dst + 8)  = make_float4(op[r][8],  op[r][9],  op[r][10], op[r][11]);
            *(float4*)(dst + 12) = make_float4(op[r][12], op[r][13], op[r][14], op[r][15]);
        }
    }
}

// ===================== host =====================
extern "C" void kernel_launch(void* const* d_in, const int* in_sizes, int n_in,
                              void* d_out, int out_size, void* d_ws, size_t ws_size,
                              hipStream_t stream)
{
    const float* x  = (const float*)d_in[0];
    const float* Wq = (const float*)d_in[1];
    const float* Wk = (const float*)d_in[2];
    const float* Wv = (const float*)d_in[3];
    const float* Eq = (const float*)d_in[4];
    const float* Ek = (const float*)d_in[5];
    const float* Ev = (const float*)d_in[6];
    const float* Wp = (const float*)d_in[7];
    const float* bp = (const float*)d_in[8];
    float* out = (float*)d_out;
    float* ws  = (float*)d_ws;

    float* q   = ws;
    float* k   = ws + (size_t)4194304;
    float* vp  = ws + (size_t)2 * 4194304;
    float* ctx = ws + (size_t)3 * 4194304;

    (void)hipFuncSetAttribute((const void*)attn_kernel,
                              hipFuncAttributeMaxDynamicSharedMemorySize, 163840);

    gemm_qkv_kernel<<<dim3(8, 32, 3), 256, 0, stream>>>(x, Wq, Wk, Wv, Ev, q, k, vp);
    attn_kernel<<<dim3(32, 64), 512, 163840, stream>>>(q, k, vp, Eq, Ek, ctx);
    gemm_out_kernel<<<dim3(8, 32, 1), 256, 0, stream>>>(ctx, Wp, bp, out);
}

// Round 7
// 1087.756 us; speedup vs baseline: 9.4061x; 1.8565x over previous
//
#include <hip/hip_runtime.h>
#include <cstdint>
#include <cstddef>

#define Nn 1024
#define Cc 1024
#define Hh 16
#define DHd 64
#define SCALE 0.125f   // DH^-0.5

typedef short  s16x8 __attribute__((ext_vector_type(8)));
typedef short  s16x4 __attribute__((ext_vector_type(4)));
typedef float  f32x4 __attribute__((ext_vector_type(4)));
#define MFMA16 __builtin_amdgcn_mfma_f32_16x16x32_bf16

__device__ __forceinline__ float b2f(short s) {
    return __uint_as_float(((unsigned int)(unsigned short)s) << 16);
}
// split x into bf16 hi (RNE) + bf16 lo (truncated residual); x ≈ hi + lo, ~2^-16 rel err.
// returns {hi, lo} by value (refs can't bind to ext-vector elements).
__device__ __forceinline__ short2 split2(float x) {
    unsigned int xb = __float_as_uint(x);
    unsigned int hb = (xb + 0x7FFFu + ((xb >> 16) & 1u)) & 0xFFFF0000u;
    short h = (short)(hb >> 16);
    float r = x - __uint_as_float(hb);
    short l = (short)(__float_as_uint(r) >> 16);
    return make_short2(h, l);
}

// ===================== 128x128 fp32 GEMM core: out = A @ W^T =====================
__device__ __forceinline__ void gemm_tile(const float* __restrict__ A,
                                          const float* __restrict__ W,
                                          int m0, int n0,
                                          float (&acc)[8][8],
                                          float (*As)[132], float (*Bs)[132])
{
    const int tid  = threadIdx.x;
    const int row  = tid >> 1;
    const int half = tid & 1;
    const int tx   = tid & 15, ty = tid >> 4;
    for (int k0 = 0; k0 < Cc; k0 += 8) {
        float4 av = *(const float4*)(A + (size_t)(m0 + row) * Cc + k0 + half * 4);
        float4 bv = *(const float4*)(W + (size_t)(n0 + row) * Cc + k0 + half * 4);
        __syncthreads();
        As[half*4+0][row] = av.x; As[half*4+1][row] = av.y;
        As[half*4+2][row] = av.z; As[half*4+3][row] = av.w;
        Bs[half*4+0][row] = bv.x; Bs[half*4+1][row] = bv.y;
        Bs[half*4+2][row] = bv.z; Bs[half*4+3][row] = bv.w;
        __syncthreads();
        #pragma unroll
        for (int kk = 0; kk < 8; ++kk) {
            float4 a0 = *(const float4*)&As[kk][ty*8];
            float4 a1 = *(const float4*)&As[kk][ty*8+4];
            float4 b0 = *(const float4*)&Bs[kk][tx*8];
            float4 b1 = *(const float4*)&Bs[kk][tx*8+4];
            float ar[8] = {a0.x,a0.y,a0.z,a0.w,a1.x,a1.y,a1.z,a1.w};
            float br[8] = {b0.x,b0.y,b0.z,b0.w,b1.x,b1.y,b1.z,b1.w};
            #pragma unroll
            for (int i = 0; i < 8; ++i)
                #pragma unroll
                for (int j = 0; j < 8; ++j)
                    acc[i][j] += ar[i] * br[j];
        }
    }
}

// q/k: write split-bf16 hi/lo (head-split layout); v: write fp32 with Er_v folded in.
__global__ __launch_bounds__(256, 2)
void gemm_qkv_kernel(const float* __restrict__ x,
                     const float* __restrict__ Wq, const float* __restrict__ Wk,
                     const float* __restrict__ Wv, const float* __restrict__ Ev,
                     short* __restrict__ qh, short* __restrict__ ql,
                     short* __restrict__ kh, short* __restrict__ kl,
                     float* __restrict__ vp)
{
    __shared__ float As[8][132];
    __shared__ float Bs[8][132];
    const int z = blockIdx.z;
    const float* W = (z == 0) ? Wq : (z == 1) ? Wk : Wv;
    const int m0 = blockIdx.y * 128, n0 = blockIdx.x * 128;
    float acc[8][8] = {};
    gemm_tile(x, W, m0, n0, acc, As, Bs);
    const int tx = threadIdx.x & 15, ty = threadIdx.x >> 4;
    #pragma unroll
    for (int i = 0; i < 8; ++i) {
        const int t  = m0 + ty*8 + i;
        const int bb = t >> 10, ii = t & 1023;
        #pragma unroll
        for (int j4 = 0; j4 < 2; ++j4) {
            const int o  = n0 + tx*8 + j4*4;
            const int hh = o >> 6, dd = o & 63;
            const size_t base = (size_t)((bb*Hh + hh)*Nn + ii) * DHd + dd;
            if (z == 2) {
                float4 e = *(const float4*)(Ev + (size_t)ii * DHd + dd);
                float4 v = make_float4(acc[i][j4*4+0]+e.x, acc[i][j4*4+1]+e.y,
                                       acc[i][j4*4+2]+e.z, acc[i][j4*4+3]+e.w);
                *(float4*)(vp + base) = v;
            } else {
                short* oh = z ? kh : qh;
                short* ol = z ? kl : ql;
                s16x4 h4, l4;
                #pragma unroll
                for (int c = 0; c < 4; ++c) {
                    short2 hl = split2(acc[i][j4*4+c]);
                    h4[c] = hl.x; l4[c] = hl.y;
                }
                *(s16x4*)(oh + base) = h4;
                *(s16x4*)(ol + base) = l4;
            }
        }
    }
}

// final projection: out = ctx @ Wp^T + bp  (fp32)
__global__ __launch_bounds__(256, 2)
void gemm_out_kernel(const float* __restrict__ ctx, const float* __restrict__ Wp,
                     const float* __restrict__ bp, float* __restrict__ out)
{
    __shared__ float As[8][132];
    __shared__ float Bs[8][132];
    const int m0 = blockIdx.y * 128, n0 = blockIdx.x * 128;
    float acc[8][8] = {};
    gemm_tile(ctx, Wp, m0, n0, acc, As, Bs);
    const int tx = threadIdx.x & 15, ty = threadIdx.x >> 4;
    #pragma unroll
    for (int i = 0; i < 8; ++i) {
        const int t = m0 + ty*8 + i;
        #pragma unroll
        for (int j4 = 0; j4 < 2; ++j4) {
            const int o = n0 + tx*8 + j4*4;
            float4 bb4 = *(const float4*)(bp + o);
            float4 v = make_float4(acc[i][j4*4+0]+bb4.x, acc[i][j4*4+1]+bb4.y,
                                   acc[i][j4*4+2]+bb4.z, acc[i][j4*4+3]+bb4.w);
            *(float4*)(out + (size_t)t * Cc + o) = v;
        }
    }
}

// Er tables (first 1024 rows) -> split bf16 hi/lo
__global__ __launch_bounds__(256)
void convert_er_kernel(const float* __restrict__ Er_q, const float* __restrict__ Er_k,
                       short* __restrict__ Eqh, short* __restrict__ Eql,
                       short* __restrict__ Ekh, short* __restrict__ Ekl)
{
    const int i4 = (blockIdx.x * 256 + threadIdx.x) * 4;   // < 65536
    float4 a = *(const float4*)(Er_q + i4);
    float4 b = *(const float4*)(Er_k + i4);
    s16x4 ah, al, bh, bl;
    float av[4] = {a.x, a.y, a.z, a.w};
    float bv[4] = {b.x, b.y, b.z, b.w};
    #pragma unroll
    for (int c = 0; c < 4; ++c) {
        short2 ha = split2(av[c]); ah[c] = ha.x; al[c] = ha.y;
        short2 hb = split2(bv[c]); bh[c] = hb.x; bl[c] = hb.y;
    }
    *(s16x4*)(Eqh + i4) = ah; *(s16x4*)(Eql + i4) = al;
    *(s16x4*)(Ekh + i4) = bh; *(s16x4*)(Ekl + i4) = bl;
}

// vp [bh][tok][d] fp32  ->  vT [bh][d][tok] split-bf16 hi/lo
__global__ __launch_bounds__(256)
void transpose_v_kernel(const float* __restrict__ vp,
                        short* __restrict__ vTh, short* __restrict__ vTl)
{
    __shared__ float T[64][65];
    const int tid = threadIdx.x;
    const int bh = blockIdx.y, t0 = blockIdx.x * 64;
    const float* src = vp + ((size_t)bh * Nn + t0) * DHd;
    #pragma unroll
    for (int rr = 0; rr < 4; ++rr) {
        const int fi = tid + 256*rr;
        const int r = fi >> 4, c = (fi & 15) * 4;
        float4 v = *(const float4*)(src + (size_t)r * 64 + c);
        T[r][c] = v.x; T[r][c+1] = v.y; T[r][c+2] = v.z; T[r][c+3] = v.w;
    }
    __syncthreads();
    const int d = tid >> 2, tg = (tid & 3) * 16;
    s16x8 h[2], l[2];
    #pragma unroll
    for (int t = 0; t < 16; ++t) {
        short2 hl = split2(T[tg + t][d]);
        h[t>>3][t&7] = hl.x; l[t>>3][t&7] = hl.y;
    }
    const size_t ob = ((size_t)bh * DHd + d) * Nn + t0 + tg;
    *(s16x8*)(vTh + ob) = h[0]; *(s16x8*)(vTh + ob + 8) = h[1];
    *(s16x8*)(vTl + ob) = l[0]; *(s16x8*)(vTl + ob + 8) = l[1];
}

// ===================== fused relative attention, split-bf16 MFMA =====================
// Block: (b,h), 32 q-rows. 8 waves; wave wv owns S cols [wv*128, wv*128+128).
// LDS: S[32][1024] fp32, col-swizzled  addr = row*1024 + (col ^ ((row&7)<<2)).
// P1: S=q@k^T (MFMA); P2: G=q@Eq^T+k@Ek^T (MFMA) skew-scattered; P3 softmax; P4 split-K PV.
__global__ __launch_bounds__(512, 2)
void attn_kernel(const short* __restrict__ qh, const short* __restrict__ ql,
                 const short* __restrict__ kh, const short* __restrict__ kl,
                 const short* __restrict__ vTh, const short* __restrict__ vTl,
                 const short* __restrict__ Eqh, const short* __restrict__ Eql,
                 const short* __restrict__ Ekh, const short* __restrict__ Ekl,
                 float* __restrict__ ctx)
{
    extern __shared__ float S[];   // 32*1024 fp32
    const int tid  = threadIdx.x;
    const int lane = tid & 63;
    const int wv   = __builtin_amdgcn_readfirstlane(tid >> 6);
    const int i0   = blockIdx.x * 32;
    const int bh   = blockIdx.y;
    const int b    = bh >> 4, h = bh & 15;
    const short* qhB = qh + (size_t)bh * Nn * DHd;
    const short* qlB = ql + (size_t)bh * Nn * DHd;
    const short* khB = kh + (size_t)bh * Nn * DHd;
    const short* klB = kl + (size_t)bh * Nn * DHd;
    const short* vThB = vTh + (size_t)bh * DHd * Nn;
    const short* vTlB = vTl + (size_t)bh * DHd * Nn;
    const int l15 = lane & 15;
    const int lk8 = (lane >> 4) * 8;

    // ---- A fragments: q rows (used in P1 & P2). A: row=l&15, k=(l>>4)*8+j ----
    s16x8 Aq[2][2][2];   // [mt][ks][hi/lo]
    #pragma unroll
    for (int mt = 0; mt < 2; ++mt)
        #pragma unroll
        for (int ks = 0; ks < 2; ++ks) {
            const size_t off = (size_t)(i0 + mt*16 + l15) * 64 + ks*32 + lk8;
            Aq[mt][ks][0] = *(const s16x8*)(qhB + off);
            Aq[mt][ks][1] = *(const s16x8*)(qlB + off);
        }

    // ---------------- Phase 1: S = q @ k^T ----------------
    #pragma unroll
    for (int nt = 0; nt < 8; ++nt) {
        const int col0 = wv*128 + nt*16;
        const size_t boff = (size_t)(col0 + l15) * 64 + lk8;
        s16x8 B0h = *(const s16x8*)(khB + boff);
        s16x8 B0l = *(const s16x8*)(klB + boff);
        s16x8 B1h = *(const s16x8*)(khB + boff + 32);
        s16x8 B1l = *(const s16x8*)(klB + boff + 32);
        f32x4 a0 = {0.f,0.f,0.f,0.f}, a1 = {0.f,0.f,0.f,0.f};
        a0 = MFMA16(Aq[0][0][0], B0h, a0, 0,0,0);
        a0 = MFMA16(Aq[0][0][0], B0l, a0, 0,0,0);
        a0 = MFMA16(Aq[0][0][1], B0h, a0, 0,0,0);
        a0 = MFMA16(Aq[0][1][0], B1h, a0, 0,0,0);
        a0 = MFMA16(Aq[0][1][0], B1l, a0, 0,0,0);
        a0 = MFMA16(Aq[0][1][1], B1h, a0, 0,0,0);
        a1 = MFMA16(Aq[1][0][0], B0h, a1, 0,0,0);
        a1 = MFMA16(Aq[1][0][0], B0l, a1, 0,0,0);
        a1 = MFMA16(Aq[1][0][1], B0h, a1, 0,0,0);
        a1 = MFMA16(Aq[1][1][0], B1h, a1, 0,0,0);
        a1 = MFMA16(Aq[1][1][0], B1l, a1, 0,0,0);
        a1 = MFMA16(Aq[1][1][1], B1h, a1, 0,0,0);
        const int colw = col0 + l15;
        #pragma unroll
        for (int r = 0; r < 4; ++r) {
            const int row0 = (lane>>4)*4 + r;                // C/D: col=l&15, row=(l>>4)*4+r
            const int sw = (row0 & 7) << 2;                  // rows row0, row0+16 share (row&7)
            S[row0*1024 + (colw ^ sw)] = a0[r];
            S[(row0+16)*1024 + (colw ^ sw)] = a1[r];
        }
    }

    // ---- A fragments: k rows (for P2) ----
    s16x8 Ak[2][2][2];
    #pragma unroll
    for (int mt = 0; mt < 2; ++mt)
        #pragma unroll
        for (int ks = 0; ks < 2; ++ks) {
            const size_t off = (size_t)(i0 + mt*16 + l15) * 64 + ks*32 + lk8;
            Ak[mt][ks][0] = *(const s16x8*)(khB + off);
            Ak[mt][ks][1] = *(const s16x8*)(klB + off);
        }

    __syncthreads();   // P1 complete across all waves

    // ---------------- Phase 2: G tiles, skew-scattered into S ----------------
    // G[gr][j] -> S[gr][j+i-1023] (c<=i) and S[gr-1][j+i+1] (c>i+1), i=i0+gr.
    // Exactly one branch fires per (gr,j); targets are address-disjoint across lanes/waves.
    #pragma unroll
    for (int nt = 0; nt < 8; ++nt) {
        const int col0 = wv*128 + nt*16;
        const size_t eoff = (size_t)(col0 + l15) * 64 + lk8;
        s16x8 Q0h = *(const s16x8*)(Eqh + eoff);
        s16x8 Q0l = *(const s16x8*)(Eql + eoff);
        s16x8 Q1h = *(const s16x8*)(Eqh + eoff + 32);
        s16x8 Q1l = *(const s16x8*)(Eql + eoff + 32);
        s16x8 K0h = *(const s16x8*)(Ekh + eoff);
        s16x8 K0l = *(const s16x8*)(Ekl + eoff);
        s16x8 K1h = *(const s16x8*)(Ekh + eoff + 32);
        s16x8 K1l = *(const s16x8*)(Ekl + eoff + 32);
        f32x4 g0 = {0.f,0.f,0.f,0.f}, g1 = {0.f,0.f,0.f,0.f};
        g0 = MFMA16(Aq[0][0][0], Q0h, g0, 0,0,0);
        g0 = MFMA16(Aq[0][0][0], Q0l, g0, 0,0,0);
        g0 = MFMA16(Aq[0][0][1], Q0h, g0, 0,0,0);
        g0 = MFMA16(Aq[0][1][0], Q1h, g0, 0,0,0);
        g0 = MFMA16(Aq[0][1][0], Q1l, g0, 0,0,0);
        g0 = MFMA16(Aq[0][1][1], Q1h, g0, 0,0,0);
        g0 = MFMA16(Ak[0][0][0], K0h, g0, 0,0,0);
        g0 = MFMA16(Ak[0][0][0], K0l, g0, 0,0,0);
        g0 = MFMA16(Ak[0][0][1], K0h, g0, 0,0,0);
        g0 = MFMA16(Ak[0][1][0], K1h, g0, 0,0,0);
        g0 = MFMA16(Ak[0][1][0], K1l, g0, 0,0,0);
        g0 = MFMA16(Ak[0][1][1], K1h, g0, 0,0,0);
        g1 = MFMA16(Aq[1][0][0], Q0h, g1, 0,0,0);
        g1 = MFMA16(Aq[1][0][0], Q0l, g1, 0,0,0);
        g1 = MFMA16(Aq[1][0][1], Q0h, g1, 0,0,0);
        g1 = MFMA16(Aq[1][1][0], Q1h, g1, 0,0,0);
        g1 = MFMA16(Aq[1][1][0], Q1l, g1, 0,0,0);
        g1 = MFMA16(Aq[1][1][1], Q1h, g1, 0,0,0);
        g1 = MFMA16(Ak[1][0][0], K0h, g1, 0,0,0);
        g1 = MFMA16(Ak[1][0][0], K0l, g1, 0,0,0);
        g1 = MFMA16(Ak[1][0][1], K0h, g1, 0,0,0);
        g1 = MFMA16(Ak[1][1][0], K1h, g1, 0,0,0);
        g1 = MFMA16(Ak[1][1][0], K1l, g1, 0,0,0);
        g1 = MFMA16(Ak[1][1][1], K1h, g1, 0,0,0);
        const int j = col0 + l15;
        #pragma unroll
        for (int mt = 0; mt < 2; ++mt) {
            #pragma unroll
            for (int r = 0; r < 4; ++r) {
                const int gr = mt*16 + (lane>>4)*4 + r;
                const float g = mt ? g1[r] : g0[r];
                const int i = i0 + gr;
                const int c1 = j + i - (Nn - 1);
                if (c1 >= 0) S[gr*1024 + (c1 ^ ((gr&7)<<2))] += g;
                const int c2 = j + i + 1;
                if (gr >= 1 && c2 < Nn) {
                    const int r2 = gr - 1;
                    S[r2*1024 + (c2 ^ ((r2&7)<<2))] += g;
                }
            }
        }
    }

    // ---- G row 32 (VALU): scatter into S row 31, cols >= i0+33 ----
    if (i0 + 32 < Nn) {
        const int i32 = i0 + 32;
        #pragma unroll
        for (int rep = 0; rep < 2; ++rep) {
            const int j = tid + rep*512;
            float acc = 0.f;
            for (int k8 = 0; k8 < 64; k8 += 8) {
                s16x8 q8h = *(const s16x8*)(qhB + (size_t)i32*64 + k8);
                s16x8 q8l = *(const s16x8*)(qlB + (size_t)i32*64 + k8);
                s16x8 k8h = *(const s16x8*)(khB + (size_t)i32*64 + k8);
                s16x8 k8l = *(const s16x8*)(klB + (size_t)i32*64 + k8);
                s16x8 eqh8 = *(const s16x8*)(Eqh + (size_t)j*64 + k8);
                s16x8 eql8 = *(const s16x8*)(Eql + (size_t)j*64 + k8);
                s16x8 ekh8 = *(const s16x8*)(Ekh + (size_t)j*64 + k8);
                s16x8 ekl8 = *(const s16x8*)(Ekl + (size_t)j*64 + k8);
                #pragma unroll
                for (int t = 0; t < 8; ++t) {
                    const float qv = b2f(q8h[t]) + b2f(q8l[t]);
                    const float kv = b2f(k8h[t]) + b2f(k8l[t]);
                    const float eq = b2f(eqh8[t]) + b2f(eql8[t]);
                    const float ek = b2f(ekh8[t]) + b2f(ekl8[t]);
                    acc += qv*eq + kv*ek;
                }
            }
            const int c2 = j + i32 + 1;
            if (c2 < Nn) S[31*1024 + (c2 ^ 28)] += acc;   // (31&7)<<2 = 28
        }
    }
    __syncthreads();   // all skew contributions in

    // ---------------- Phase 3: row softmax (swizzle-aware) ----------------
    const int r0 = wv * 4;
    #pragma unroll
    for (int rr = 0; rr < 4; ++rr) {
        const int row = r0 + rr;
        float* Srow = S + row*1024;
        const int sw = (row & 7) << 2;
        float vals[16];
        float m = -3.0e38f;
        #pragma unroll
        for (int x = 0; x < 16; ++x) { vals[x] = Srow[(lane ^ sw) + x*64]; m = fmaxf(m, vals[x]); }
        #pragma unroll
        for (int off = 32; off >= 1; off >>= 1) m = fmaxf(m, __shfl_xor(m, off));
        float sum = 0.f;
        #pragma unroll
        for (int x = 0; x < 16; ++x) { vals[x] = __expf((vals[x] - m) * SCALE); sum += vals[x]; }
        #pragma unroll
        for (int off = 32; off >= 1; off >>= 1) sum += __shfl_xor(sum, off);
        const float inv = 1.0f / sum;
        #pragma unroll
        for (int x = 0; x < 16; ++x) Srow[(lane ^ sw) + x*64] = vals[x] * inv;
    }
    __syncthreads();   // P4 reads all 32 rows of this wave's k-slab

    // ---------------- Phase 4: ctx = P @ V', split-K across waves ----------------
    // wave wv covers keys [wv*128, wv*128+128); partials reduced via LDS.
    s16x8 Ph[2][4], Pl[2][4];
    #pragma unroll
    for (int mt = 0; mt < 2; ++mt)
        #pragma unroll
        for (int ksl = 0; ksl < 4; ++ksl) {
            const int row = mt*16 + l15;
            const int sw = (row & 7) << 2;
            const int cb = wv*128 + ksl*32 + lk8;
            const int ib = row*1024 + (cb ^ sw);
            float4 x0 = *(const float4*)&S[ib];
            float4 x1 = *(const float4*)&S[ib ^ 4];
            float xs[8] = {x0.x,x0.y,x0.z,x0.w,x1.x,x1.y,x1.z,x1.w};
            #pragma unroll
            for (int e = 0; e < 8; ++e) {
                short2 hl = split2(xs[e]);
                Ph[mt][ksl][e] = hl.x; Pl[mt][ksl][e] = hl.y;
            }
        }
    f32x4 o[2][4];
    #pragma unroll
    for (int mt = 0; mt < 2; ++mt)
        #pragma unroll
        for (int nt = 0; nt < 4; ++nt) o[mt][nt] = {0.f,0.f,0.f,0.f};
    #pragma unroll
    for (int ksl = 0; ksl < 4; ++ksl) {
        const size_t kk = (size_t)wv*128 + ksl*32 + lk8;
        #pragma unroll
        for (int nt = 0; nt < 4; ++nt) {
            const size_t voff = (size_t)(nt*16 + l15) * Nn + kk;
            s16x8 Vh = *(const s16x8*)(vThB + voff);
            s16x8 Vl = *(const s16x8*)(vTlB + voff);
            o[0][nt] = MFMA16(Ph[0][ksl], Vh, o[0][nt], 0,0,0);
            o[0][nt] = MFMA16(Ph[0][ksl], Vl, o[0][nt], 0,0,0);
            o[0][nt] = MFMA16(Pl[0][ksl], Vh, o[0][nt], 0,0,0);
            o[1][nt] = MFMA16(Ph[1][ksl], Vh, o[1][nt], 0,0,0);
            o[1][nt] = MFMA16(Ph[1][ksl], Vl, o[1][nt], 0,0,0);
            o[1][nt] = MFMA16(Pl[1][ksl], Vh, o[1][nt], 0,0,0);
        }
    }
    __syncthreads();   // S reads done; safe to overwrite with partials
    #pragma unroll
    for (int mt = 0; mt < 2; ++mt)
        #pragma unroll
        for (int nt = 0; nt < 4; ++nt)
            #pragma unroll
            for (int r = 0; r < 4; ++r)
                S[wv*2048 + (mt*16 + (lane>>4)*4 + r)*64 + nt*16 + l15] = o[mt][nt][r];
    __syncthreads();
    // reduce 8 partials, write ctx
    const int e = tid * 4;
    f32x4 s = *(const f32x4*)&S[e];
    #pragma unroll
    for (int w2 = 1; w2 < 8; ++w2) s += *(const f32x4*)&S[w2*2048 + e];
    const int orow = e >> 6, od = e & 63;
    *(f32x4*)&ctx[((size_t)b*Nn + i0 + orow)*Cc + h*64 + od] = s;
}

// ===================== host =====================
extern "C" void kernel_launch(void* const* d_in, const int* in_sizes, int n_in,
                              void* d_out, int out_size, void* d_ws, size_t ws_size,
                              hipStream_t stream)
{
    const float* x  = (const float*)d_in[0];
    const float* Wq = (const float*)d_in[1];
    const float* Wk = (const float*)d_in[2];
    const float* Wv = (const float*)d_in[3];
    const float* Eq = (const float*)d_in[4];
    const float* Ek = (const float*)d_in[5];
    const float* Ev = (const float*)d_in[6];
    const float* Wp = (const float*)d_in[7];
    const float* bp = (const float*)d_in[8];
    float* out = (float*)d_out;

    // ws layout (65 MiB total): vp (fp32 V staging) is dead after transpose_v,
    // so ctx aliases it.
    const size_t MB = 1u << 20;
    char* w = (char*)d_ws;
    short* qh  = (short*)(w + 0*MB);             // 8 MiB each
    short* ql  = (short*)(w + 8*MB);
    short* kh  = (short*)(w + 16*MB);
    short* kl  = (short*)(w + 24*MB);
    short* vTh = (short*)(w + 32*MB);
    short* vTl = (short*)(w + 40*MB);
    short* Eqh = (short*)(w + 48*MB);            // 128 KiB each
    short* Eql = (short*)(w + 48*MB + 128*1024);
    short* Ekh = (short*)(w + 48*MB + 256*1024);
    short* Ekl = (short*)(w + 48*MB + 384*1024);
    float* vp  = (float*)(w + 49*MB);            // 16 MiB
    float* ctx = (float*)(w + 49*MB);            // aliases vp (vp dead by then)

    (void)hipFuncSetAttribute((const void*)attn_kernel,
                              hipFuncAttributeMaxDynamicSharedMemorySize, 131072);

    convert_er_kernel<<<64, 256, 0, stream>>>(Eq, Ek, Eqh, Eql, Ekh, Ekl);
    gemm_qkv_kernel<<<dim3(8, 32, 3), 256, 0, stream>>>(x, Wq, Wk, Wv, Ev,
                                                        qh, ql, kh, kl, vp);
    transpose_v_kernel<<<dim3(16, 64), 256, 0, stream>>>(vp, vTh, vTl);
    attn_kernel<<<dim3(32, 64), 512, 131072, stream>>>(qh, ql, kh, kl, vTh, vTl,
                                                       Eqh, Eql, Ekh, Ekl, ctx);
    gemm_out_kernel<<<dim3(8, 32, 1), 256, 0, stream>>>(ctx, Wp, bp, out);
}